// Round 5
// baseline (783.462 us; speedup 1.0000x reference)
//
#include <hip/hip_runtime.h>
#include <cfloat>
#include <cmath>

#define F_IN 128
#define HID 512

typedef short bf16x8 __attribute__((ext_vector_type(8)));
typedef float f32x4 __attribute__((ext_vector_type(4)));

// ---- bf16 split helpers (RNE) ----
__device__ static inline void split_bf16(float v, short& hi, short& lo) {
    unsigned u = __float_as_uint(v);
    unsigned r = u + 0x7FFF + ((u >> 16) & 1);
    hi = (short)(r >> 16);
    float hf = __uint_as_float(((unsigned)(unsigned short)hi) << 16);
    float res = v - hf;
    unsigned u2 = __float_as_uint(res);
    unsigned r2 = u2 + 0x7FFF + ((u2 >> 16) & 1);
    lo = (short)(r2 >> 16);
}

__device__ static inline void gload_lds16(const void* g, void* l) {
    __builtin_amdgcn_global_load_lds(
        (const __attribute__((address_space(1))) unsigned int*)g,
        (__attribute__((address_space(3))) unsigned int*)l,
        16, 0, 0);
}

// ---------------- small utility kernels ----------------

__global__ void zero_kernel(int* __restrict__ a, int n) {
    int i = blockIdx.x * blockDim.x + threadIdx.x;
    if (i < n) a[i] = 0;
}

__global__ void count_in_kernel(const int* __restrict__ dst, int* __restrict__ cnt, int E) {
    int e = blockIdx.x * blockDim.x + threadIdx.x;
    if (e < E) atomicAdd(&cnt[dst[e]], 1);
}

// single-block scan (exclusive prefix sum); also writes offs[n] = total
__global__ void scan_kernel(const int* __restrict__ cnt, int* __restrict__ offs, int n) {
    __shared__ int buf[1024];
    __shared__ int carry_s;
    if (threadIdx.x == 0) carry_s = 0;
    __syncthreads();
    for (int base = 0; base < n; base += 1024) {
        int i = base + threadIdx.x;
        int v = (i < n) ? cnt[i] : 0;
        buf[threadIdx.x] = v;
        __syncthreads();
        for (int s = 1; s < 1024; s <<= 1) {
            int t = (threadIdx.x >= s) ? buf[threadIdx.x - s] : 0;
            __syncthreads();
            buf[threadIdx.x] += t;
            __syncthreads();
        }
        int total = buf[1023];
        if (i < n) offs[i] = carry_s + buf[threadIdx.x] - v;
        __syncthreads();
        if (threadIdx.x == 0) carry_s += total;
        __syncthreads();
    }
    if (threadIdx.x == 0) offs[n] = carry_s;
}

// dis (rsqrt) + rdis (sqrt, for pool unscale) + graph-boundary starts
__global__ void dis_starts_kernel(const int* __restrict__ offs, float* __restrict__ dis,
                                  float* __restrict__ rdis,
                                  const int* __restrict__ batch, int* __restrict__ starts,
                                  int n, int G) {
    int i = blockIdx.x * blockDim.x + threadIdx.x;
    if (i >= n) return;
    float degp1 = (float)(offs[i + 1] - offs[i] + 1);  // +1 self-loop
    dis[i] = rsqrtf(degp1);
    rdis[i] = sqrtf(degp1);
    int b = batch[i];
    if (i == 0) {
        for (int g = 0; g <= b; g++) starts[g] = 0;
    } else {
        int bp = batch[i - 1];
        for (int g = bp + 1; g <= b; g++) starts[g] = i;
    }
    if (i == n - 1) {
        for (int g = b + 1; g <= G; g++) starts[g] = n;
    }
}

// countdown-cursor fill: reuses cnt (holds deg) as cursor via atomicSub
__global__ void fill_csr_kernel(const int* __restrict__ src, const int* __restrict__ dst,
                                const int* __restrict__ offs, int* __restrict__ cnt,
                                unsigned short* __restrict__ csr, int E) {
    int e = blockIdx.x * blockDim.x + threadIdx.x;
    if (e < E) {
        int d = dst[e];
        int p = atomicSub(&cnt[d], 1);  // returns old value in [1, deg]
        csr[offs[d] + p - 1] = (unsigned short)src[e];
    }
}

// all-layer W fp32 -> bf16 hi/lo planes (single launch, concatenated)
__global__ void wconv_kernel(const float* __restrict__ W1, const float* __restrict__ W2,
                             const float* __restrict__ W3, const float* __restrict__ W4,
                             short* __restrict__ Whi, short* __restrict__ Wlo) {
    int i = blockIdx.x * blockDim.x + threadIdx.x;
    const int n1 = HID * F_IN, nk = HID * HID;
    float v;
    if (i < n1) v = W1[i];
    else if (i < n1 + nk) v = W2[i - n1];
    else if (i < n1 + 2 * nk) v = W3[i - n1 - nk];
    else if (i < n1 + 3 * nk) v = W4[i - n1 - 2 * nk];
    else return;
    short h, l;
    split_bf16(v, h, l);
    Whi[i] = h;
    Wlo[i] = l;
}

// layer-1 input prescale: xs[i][c] = dis[i] * x[i][c]  (F_IN = 128)
__global__ void xscale_kernel(const float* __restrict__ x, const float* __restrict__ dis,
                              float* __restrict__ xs, int total) {
    int i = blockIdx.x * blockDim.x + threadIdx.x;
    if (i < total) xs[i] = x[i] * dis[i >> 7];
}

// -------- L2-phased 32-col gather aggregation (pre-scaled rows) --------
// Input Hs holds dis_j * H_j rows, so out_i = dis_i * (Hs_i + sum_edges Hs_j):
// NO per-edge dis load. csr indices: one coalesced 64-wide load per window,
// distributed via __shfl (ds_bpermute) - no dependent csr->gather round trip.
// 16 edges in flight per wave (8 load instrs x 2 addresses). 32-col slices
// (2.56 MB/XCD, L2-fit: R1-measured FETCH 108->29 MB) with phase-major block
// order. All shfl sites are exec-uniform (uniform trip counts; tail guards
// only the accumulate).
template <int F, int CHUNKS>
__global__ __launch_bounds__(64) void agg_gather_kernel(
    const float* __restrict__ Hs, const float* __restrict__ dis,
    const int* __restrict__ offs, const unsigned short* __restrict__ csr,
    short* __restrict__ Ahi, short* __restrict__ Alo, int n) {
    constexpr int LOWB = (CHUNKS >= 8) ? 8 : CHUNKS;
    constexpr int LB = (CHUNKS >= 8) ? 3 : 2;
    constexpr int PHASES = CHUNKS / LOWB;   // 1 or 2
    int blk = blockIdx.x;
    int c_lo = blk & (LOWB - 1);
    int rest = blk >> LB;
    int p = 0, i = rest;
    if (PHASES > 1 && rest >= n) { p = 1; i = rest - n; }
    int chunk = p * LOWB + c_lo;

    int tid = threadIdx.x;
    int half = tid >> 5;          // which edge parity this half-wave owns
    int lc = tid & 31;            // column within the 32-col slice
    int col = chunk * 32 + lc;
    const float* Hc = Hs + col;

    int e0 = offs[i], e1 = offs[i + 1];
    float a = (half == 0) ? Hc[(size_t)i * F] : 0.0f;   // self term (pre-scaled)

    for (int w = e0; w < e1; w += 64) {
        int cnt = e1 - w; if (cnt > 64) cnt = 64;
        int idx = 0;
        if (tid < cnt) idx = csr[w + tid];   // coalesced 2B x cnt
        int tb = 0;
        for (; tb + 16 <= cnt; tb += 16) {   // uniform trip count
            int j0 = __shfl(idx, tb + half,      64);
            int j1 = __shfl(idx, tb + half + 2,  64);
            int j2 = __shfl(idx, tb + half + 4,  64);
            int j3 = __shfl(idx, tb + half + 6,  64);
            int j4 = __shfl(idx, tb + half + 8,  64);
            int j5 = __shfl(idx, tb + half + 10, 64);
            int j6 = __shfl(idx, tb + half + 12, 64);
            int j7 = __shfl(idx, tb + half + 14, 64);
            float r0 = Hc[(size_t)j0 * F];
            float r1 = Hc[(size_t)j1 * F];
            float r2 = Hc[(size_t)j2 * F];
            float r3 = Hc[(size_t)j3 * F];
            float r4 = Hc[(size_t)j4 * F];
            float r5 = Hc[(size_t)j5 * F];
            float r6 = Hc[(size_t)j6 * F];
            float r7 = Hc[(size_t)j7 * F];
            a += ((r0 + r1) + (r2 + r3)) + ((r4 + r5) + (r6 + r7));
        }
        for (int t = tb; t < cnt; t += 2) {  // uniform trip count; guarded accum
            int tt = t + half;
            int j = __shfl(idx, (tt < 64) ? tt : 0, 64);
            if (tt < cnt) a += Hc[(size_t)j * F];
        }
    }
    a += __shfl_xor(a, 32, 64);   // combine the two edge-parity halves
    a *= dis[i];
    if (half == 0) {
        short h, l;
        split_bf16(a, h, l);
        Ahi[(size_t)i * F + col] = h;
        Alo[(size_t)i * F + col] = l;
    }
}

// -------- split-bf16 MFMA GEMM: Hs[M,N] = dis[m] * (A[M,K] @ W[N,K]^T + bias) --------
// A,W as bf16 hi/lo planes; 3 products hi*hi + hi*lo + lo*hi.
// Epilogue writes the dis-PRESCALED activation (consumed by next agg directly;
// pool unscales with rdis). Same write volume as before.
__global__ __launch_bounds__(256) void gemm_mfma_kernel(
    const short* __restrict__ Ahi, const short* __restrict__ Alo,
    const short* __restrict__ Whi, const short* __restrict__ Wlo,
    const float* __restrict__ bias, const float* __restrict__ dis,
    float* __restrict__ Hs,
    int M, int K, int Nout, int MT, int MT8) {
    __shared__ __attribute__((aligned(16))) short lds[4][4096];

    // swizzled block decode: blk = xcd + 8*(n0t + 4*mt_local)
    int blk = blockIdx.x;
    int xcd = blk & 7;
    int r = blk >> 3;
    int n0t = r & 3;
    int mt = xcd * MT8 + (r >> 2);
    if (mt >= MT) return;                 // uniform across block; no barrier reached
    int m0 = mt * 128, n0 = n0t * 128;

    int tid = threadIdx.x;
    int w = tid >> 6, l = tid & 63;
    int lrow = l & 15, lq = l >> 4;

    const short* gp = (w == 0) ? Ahi : (w == 1) ? Alo : (w == 2) ? Whi : Wlo;
    int base_mn = (w < 2) ? m0 : n0;

    f32x4 acc[4][4];
    #pragma unroll
    for (int i = 0; i < 4; i++)
        #pragma unroll
        for (int j = 0; j < 4; j++) acc[i][j] = (f32x4){0.f, 0.f, 0.f, 0.f};

    int wm = w >> 1, wn = w & 1;

    for (int k0 = 0; k0 < K; k0 += 32) {
        const short* gbase = gp + (size_t)(base_mn + lrow) * K + (k0 + lq * 8);
        #pragma unroll
        for (int s = 0; s < 8; s++) {
            gload_lds16(gbase + (size_t)s * 16 * K, &lds[w][s * 64 * 8]);
        }
        __syncthreads();

        bf16x8 ah[4], al[4], wh[4], wl[4];
        #pragma unroll
        for (int i = 0; i < 4; i++) {
            int sA = wm * 4 + i;
            ah[i] = *(const bf16x8*)&lds[0][(sA * 64 + l) * 8];
            al[i] = *(const bf16x8*)&lds[1][(sA * 64 + l) * 8];
            int sW = wn * 4 + i;
            wh[i] = *(const bf16x8*)&lds[2][(sW * 64 + l) * 8];
            wl[i] = *(const bf16x8*)&lds[3][(sW * 64 + l) * 8];
        }
        #pragma unroll
        for (int i = 0; i < 4; i++)
            #pragma unroll
            for (int j = 0; j < 4; j++) {
                acc[i][j] = __builtin_amdgcn_mfma_f32_16x16x32_bf16(ah[i], wh[j], acc[i][j], 0, 0, 0);
                acc[i][j] = __builtin_amdgcn_mfma_f32_16x16x32_bf16(ah[i], wl[j], acc[i][j], 0, 0, 0);
                acc[i][j] = __builtin_amdgcn_mfma_f32_16x16x32_bf16(al[i], wh[j], acc[i][j], 0, 0, 0);
            }
        __syncthreads();
    }

    // hoisted per-row dis loads (16 independent, latency-hidden)
    float dv[4][4];
    #pragma unroll
    for (int i = 0; i < 4; i++) {
        int mrow = m0 + (wm * 4 + i) * 16 + lq * 4;
        #pragma unroll
        for (int rr = 0; rr < 4; rr++) {
            int mm = mrow + rr;
            dv[i][rr] = (mm < M) ? dis[mm] : 0.0f;
        }
    }

    // epilogue: C/D layout col=lane&15, row=(lane>>4)*4+reg
    #pragma unroll
    for (int j = 0; j < 4; j++) {
        int col = n0 + (wn * 4 + j) * 16 + lrow;
        float bv = bias[col];
        #pragma unroll
        for (int i = 0; i < 4; i++) {
            int mrow = m0 + (wm * 4 + i) * 16 + lq * 4;
            #pragma unroll
            for (int rr = 0; rr < 4; rr++) {
                int mm = mrow + rr;
                if (mm < M) Hs[(size_t)mm * Nout + col] = dv[i][rr] * (acc[i][j][rr] + bv);
            }
        }
    }
}

// ---------------- pooling: per-layer segment max + fraction positive ----------------
// grid (G, 8), 64 threads. Input is the dis-prescaled Hs; unscale with rdis[n].
__global__ __launch_bounds__(64) void pool_kernel(
    const float* __restrict__ Hs, const float* __restrict__ rdis,
    const int* __restrict__ starts,
    float* __restrict__ out, int layer) {
    int g = blockIdx.x;
    int c = blockIdx.y * 64 + threadIdx.x;   // 0..511
    int s = starts[g], e = starts[g + 1];
    float mx = -INFINITY;
    int pos = 0;
    #pragma unroll 4
    for (int n = s; n < e; n++) {
        float v = Hs[(size_t)n * HID + c] * rdis[n];
        mx = fmaxf(mx, v);
        pos += (v > 0.0f) ? 1 : 0;
    }
    float cntf = fmaxf((float)(e - s), 1.0f);
    out[(size_t)g * (8 * HID) + layer * HID + c] = mx;
    out[(size_t)g * (8 * HID) + 4 * HID + layer * HID + c] = (float)pos / cntf;
}

// ---------------- launcher ----------------
extern "C" void kernel_launch(void* const* d_in, const int* in_sizes, int n_in,
                              void* d_out, int out_size, void* d_ws, size_t ws_size,
                              hipStream_t stream) {
    const float* x     = (const float*)d_in[0];
    const int*   eidx  = (const int*)d_in[1];
    const int*   batch = (const int*)d_in[2];
    const float* W1 = (const float*)d_in[5];
    const float* b1 = (const float*)d_in[6];
    const float* W2 = (const float*)d_in[7];
    const float* b2 = (const float*)d_in[8];
    const float* W3 = (const float*)d_in[9];
    const float* b3 = (const float*)d_in[10];
    const float* W4 = (const float*)d_in[11];
    const float* b4 = (const float*)d_in[12];
    float* out = (float*)d_out;

    const int N = in_sizes[0] / F_IN;   // 20000
    const int E = in_sizes[1] / 2;      // 320000
    const int G = out_size / (8 * HID); // 256

    const int* src = eidx;
    const int* dst = eidx + E;

    // workspace layout (16B-aligned segments first)
    const size_t nW = (size_t)HID * F_IN + 3 * (size_t)HID * HID;
    char* w = (char*)d_ws;
    short* Ahi = (short*)w; w += (size_t)N * HID * sizeof(short);
    short* Alo = (short*)w; w += (size_t)N * HID * sizeof(short);
    float* Hs  = (float*)w; w += (size_t)N * HID * sizeof(float);
    float* xs  = (float*)w; w += (size_t)N * F_IN * sizeof(float);
    short* Whi = (short*)w; w += nW * sizeof(short);
    short* Wlo = (short*)w; w += nW * sizeof(short);
    int* offs  = (int*)w;   w += (size_t)(N + 4) * sizeof(int);
    unsigned short* csr = (unsigned short*)w; w += (size_t)E * sizeof(unsigned short);
    int* cnt   = (int*)w;   w += (size_t)N * sizeof(int);
    float* dis = (float*)w; w += (size_t)N * sizeof(float);
    float* rdis = (float*)w; w += (size_t)N * sizeof(float);
    int* starts = (int*)w;  w += (size_t)(G + 1) * sizeof(int);

    const size_t wo1 = 0;
    const size_t wo2 = (size_t)HID * F_IN;
    const size_t wo3 = wo2 + (size_t)HID * HID;
    const size_t wo4 = wo3 + (size_t)HID * HID;

    const int TB = 256;
    // ---- preprocessing: CSR over dst, dis, graph boundaries, W planes ----
    zero_kernel<<<(N + TB - 1) / TB, TB, 0, stream>>>(cnt, N);
    count_in_kernel<<<(E + TB - 1) / TB, TB, 0, stream>>>(dst, cnt, E);
    scan_kernel<<<1, 1024, 0, stream>>>(cnt, offs, N);
    dis_starts_kernel<<<(N + TB - 1) / TB, TB, 0, stream>>>(offs, dis, rdis, batch, starts, N, G);
    fill_csr_kernel<<<(E + TB - 1) / TB, TB, 0, stream>>>(src, dst, offs, cnt, csr, E);
    wconv_kernel<<<((int)nW + TB - 1) / TB, TB, 0, stream>>>(W1, W2, W3, W4, Whi, Wlo);
    xscale_kernel<<<(N * F_IN + TB - 1) / TB, TB, 0, stream>>>(x, dis, xs, N * F_IN);

    const int MT = (N + 127) / 128;        // 157 m-tiles
    const int MT8 = (MT + 7) / 8;          // per-XCD band
    const int gemm_blocks = 8 * MT8 * 4;   // 1D swizzled grid (some idle-guarded)
    dim3 pool_grid(G, HID / 64);

    // ---- layer 1: h1 = (A x) @ W1^T + b1 ----
    agg_gather_kernel<F_IN, 4><<<N * 4, 64, 0, stream>>>(xs, dis, offs, csr, Ahi, Alo, N);
    gemm_mfma_kernel<<<gemm_blocks, 256, 0, stream>>>(Ahi, Alo, Whi + wo1, Wlo + wo1, b1, dis, Hs,
                                                      N, F_IN, HID, MT, MT8);
    pool_kernel<<<pool_grid, 64, 0, stream>>>(Hs, rdis, starts, out, 0);

    // ---- layers 2..4 ----
    const size_t wos[3] = {wo2, wo3, wo4};
    const float* bs_[3] = {b2, b3, b4};
    for (int ll = 0; ll < 3; ll++) {
        agg_gather_kernel<HID, 16><<<N * 16, 64, 0, stream>>>(Hs, dis, offs, csr, Ahi, Alo, N);
        gemm_mfma_kernel<<<gemm_blocks, 256, 0, stream>>>(Ahi, Alo, Whi + wos[ll], Wlo + wos[ll], bs_[ll], dis, Hs,
                                                          N, HID, HID, MT, MT8);
        pool_kernel<<<pool_grid, 64, 0, stream>>>(Hs, rdis, starts, out, ll + 1);
    }
}

// Round 6
// 756.868 us; speedup vs baseline: 1.0351x; 1.0351x over previous
//
#include <hip/hip_runtime.h>
#include <cfloat>
#include <cmath>

#define F_IN 128
#define HID 512

typedef short bf16x8 __attribute__((ext_vector_type(8)));
typedef float f32x4 __attribute__((ext_vector_type(4)));

// ---- bf16 split helpers (RNE) ----
__device__ static inline void split_bf16(float v, short& hi, short& lo) {
    unsigned u = __float_as_uint(v);
    unsigned r = u + 0x7FFF + ((u >> 16) & 1);
    hi = (short)(r >> 16);
    float hf = __uint_as_float(((unsigned)(unsigned short)hi) << 16);
    float res = v - hf;
    unsigned u2 = __float_as_uint(res);
    unsigned r2 = u2 + 0x7FFF + ((u2 >> 16) & 1);
    lo = (short)(r2 >> 16);
}

__device__ static inline void gload_lds16(const void* g, void* l) {
    __builtin_amdgcn_global_load_lds(
        (const __attribute__((address_space(1))) unsigned int*)g,
        (__attribute__((address_space(3))) unsigned int*)l,
        16, 0, 0);
}

// ---------------- small utility kernels ----------------

__global__ void zero_kernel(int* __restrict__ a, int n) {
    int i = blockIdx.x * blockDim.x + threadIdx.x;
    if (i < n) a[i] = 0;
}

__global__ void count_in_kernel(const int* __restrict__ dst, int* __restrict__ cnt, int E) {
    int e = blockIdx.x * blockDim.x + threadIdx.x;
    if (e < E) atomicAdd(&cnt[dst[e]], 1);
}

// single-block scan (exclusive prefix sum); also writes offs[n] = total
__global__ void scan_kernel(const int* __restrict__ cnt, int* __restrict__ offs, int n) {
    __shared__ int buf[1024];
    __shared__ int carry_s;
    if (threadIdx.x == 0) carry_s = 0;
    __syncthreads();
    for (int base = 0; base < n; base += 1024) {
        int i = base + threadIdx.x;
        int v = (i < n) ? cnt[i] : 0;
        buf[threadIdx.x] = v;
        __syncthreads();
        for (int s = 1; s < 1024; s <<= 1) {
            int t = (threadIdx.x >= s) ? buf[threadIdx.x - s] : 0;
            __syncthreads();
            buf[threadIdx.x] += t;
            __syncthreads();
        }
        int total = buf[1023];
        if (i < n) offs[i] = carry_s + buf[threadIdx.x] - v;
        __syncthreads();
        if (threadIdx.x == 0) carry_s += total;
        __syncthreads();
    }
    if (threadIdx.x == 0) offs[n] = carry_s;
}

// dis (rsqrt) + rdis (sqrt, for pool unscale) + graph-boundary starts
__global__ void dis_starts_kernel(const int* __restrict__ offs, float* __restrict__ dis,
                                  float* __restrict__ rdis,
                                  const int* __restrict__ batch, int* __restrict__ starts,
                                  int n, int G) {
    int i = blockIdx.x * blockDim.x + threadIdx.x;
    if (i >= n) return;
    float degp1 = (float)(offs[i + 1] - offs[i] + 1);  // +1 self-loop
    dis[i] = rsqrtf(degp1);
    rdis[i] = sqrtf(degp1);
    int b = batch[i];
    if (i == 0) {
        for (int g = 0; g <= b; g++) starts[g] = 0;
    } else {
        int bp = batch[i - 1];
        for (int g = bp + 1; g <= b; g++) starts[g] = i;
    }
    if (i == n - 1) {
        for (int g = b + 1; g <= G; g++) starts[g] = n;
    }
}

// countdown-cursor fill: reuses cnt (holds deg) as cursor via atomicSub
__global__ void fill_csr_kernel(const int* __restrict__ src, const int* __restrict__ dst,
                                const int* __restrict__ offs, int* __restrict__ cnt,
                                unsigned short* __restrict__ csr, int E) {
    int e = blockIdx.x * blockDim.x + threadIdx.x;
    if (e < E) {
        int d = dst[e];
        int p = atomicSub(&cnt[d], 1);  // returns old value in [1, deg]
        csr[offs[d] + p - 1] = (unsigned short)src[e];
    }
}

// all-layer W fp32 -> bf16 hi/lo planes (single launch, concatenated)
__global__ void wconv_kernel(const float* __restrict__ W1, const float* __restrict__ W2,
                             const float* __restrict__ W3, const float* __restrict__ W4,
                             short* __restrict__ Whi, short* __restrict__ Wlo) {
    int i = blockIdx.x * blockDim.x + threadIdx.x;
    const int n1 = HID * F_IN, nk = HID * HID;
    float v;
    if (i < n1) v = W1[i];
    else if (i < n1 + nk) v = W2[i - n1];
    else if (i < n1 + 2 * nk) v = W3[i - n1 - nk];
    else if (i < n1 + 3 * nk) v = W4[i - n1 - 2 * nk];
    else return;
    short h, l;
    split_bf16(v, h, l);
    Whi[i] = h;
    Wlo[i] = l;
}

// layer-1 input prescale: xs[i][c] = dis[i] * x[i][c]  (F_IN = 128)
__global__ void xscale_kernel(const float* __restrict__ x, const float* __restrict__ dis,
                              float* __restrict__ xs, int total) {
    int i = blockIdx.x * blockDim.x + threadIdx.x;
    if (i < total) xs[i] = x[i] * dis[i >> 7];
}

// -------- L2-phased 32-col gather aggregation, 4 nodes per 256-thread block --------
// R5 post-mortem: 320K 1-wave WGs ran at 1.33 WG/cycle = plausible dispatch-rate
// ceiling (no pipe saturated, FETCH fine). Fix (a): 4 waves/block = 4 consecutive
// nodes, same chunk -> 4x fewer WGs, same wave count, XCD pinning (blk%LOWB) and
// phase-major order preserved. Fix (b): avg degree = 16, Poisson tail put ~46% of
// nodes into the serial 2-edge-step tail; now ALL batches are full-width 16-edge
// predicated batches (loads unconditional on shfl'd valid index, accumulate
// masked) -> ceil(deg/16) fully-pipelined rounds, 8 loads/lane in flight.
// Rows pre-scaled by dis (no per-edge dis load); 32-col slices stay L2-resident
// (R5-measured FETCH 29 MB).
template <int F, int CHUNKS>
__global__ __launch_bounds__(256) void agg_gather_kernel(
    const float* __restrict__ Hs, const float* __restrict__ dis,
    const int* __restrict__ offs, const unsigned short* __restrict__ csr,
    short* __restrict__ Ahi, short* __restrict__ Alo, int n) {
    constexpr int LOWB = (CHUNKS >= 8) ? 8 : CHUNKS;
    constexpr int LB = (CHUNKS >= 8) ? 3 : 2;
    constexpr int PHASES = CHUNKS / LOWB;   // 1 or 2
    int blk = blockIdx.x;
    int c_lo = blk & (LOWB - 1);
    int gt = blk >> LB;                     // node-group, phase-major
    int ng = (n + 3) >> 2;
    int p = 0;
    if (PHASES > 1 && gt >= ng) { p = 1; gt -= ng; }
    int wave = threadIdx.x >> 6;
    int i = gt * 4 + wave;                  // this wave's node
    if (i >= n) return;                     // wave-uniform; no barriers in kernel
    int chunk = p * LOWB + c_lo;

    int tid = threadIdx.x & 63;
    int half = tid >> 5;          // edge-parity half-wave
    int lc = tid & 31;            // column within the 32-col slice
    int col = chunk * 32 + lc;
    const float* Hc = Hs + col;

    int e0 = offs[i], e1 = offs[i + 1];
    float di = dis[i];
    float a = (half == 0) ? Hc[(size_t)i * F] : 0.0f;   // self term (pre-scaled)

    for (int w0 = e0; w0 < e1; w0 += 64) {
        int cnt = e1 - w0; if (cnt > 64) cnt = 64;
        int idx = 0;                         // lanes >= cnt: row 0 (valid, L1-hot)
        if (tid < cnt) idx = csr[w0 + tid];  // coalesced 2B x cnt
        int nb = (cnt + 15) >> 4;            // uniform trip count
        for (int b = 0; b < nb; b++) {
            int tb = b * 16 + half;
            int j0 = __shfl(idx, tb,      64);
            int j1 = __shfl(idx, tb + 2,  64);
            int j2 = __shfl(idx, tb + 4,  64);
            int j3 = __shfl(idx, tb + 6,  64);
            int j4 = __shfl(idx, tb + 8,  64);
            int j5 = __shfl(idx, tb + 10, 64);
            int j6 = __shfl(idx, tb + 12, 64);
            int j7 = __shfl(idx, tb + 14, 64);
            float r0 = Hc[(size_t)j0 * F];
            float r1 = Hc[(size_t)j1 * F];
            float r2 = Hc[(size_t)j2 * F];
            float r3 = Hc[(size_t)j3 * F];
            float r4 = Hc[(size_t)j4 * F];
            float r5 = Hc[(size_t)j5 * F];
            float r6 = Hc[(size_t)j6 * F];
            float r7 = Hc[(size_t)j7 * F];
            // predicated accumulate (loads above are unconditional & valid)
            a += (tb      < cnt) ? r0 : 0.0f;
            a += (tb + 2  < cnt) ? r1 : 0.0f;
            a += (tb + 4  < cnt) ? r2 : 0.0f;
            a += (tb + 6  < cnt) ? r3 : 0.0f;
            a += (tb + 8  < cnt) ? r4 : 0.0f;
            a += (tb + 10 < cnt) ? r5 : 0.0f;
            a += (tb + 12 < cnt) ? r6 : 0.0f;
            a += (tb + 14 < cnt) ? r7 : 0.0f;
        }
    }
    a += __shfl_xor(a, 32, 64);   // combine the two edge-parity halves
    a *= di;
    if (half == 0) {
        short h, l;
        split_bf16(a, h, l);
        Ahi[(size_t)i * F + col] = h;
        Alo[(size_t)i * F + col] = l;
    }
}

// -------- split-bf16 MFMA GEMM: Hs[M,N] = dis[m] * (A[M,K] @ W[N,K]^T + bias) --------
// A,W as bf16 hi/lo planes; 3 products hi*hi + hi*lo + lo*hi.
// Epilogue writes the dis-PRESCALED activation (consumed by next agg directly;
// pool unscales with rdis). Same write volume as before.
__global__ __launch_bounds__(256) void gemm_mfma_kernel(
    const short* __restrict__ Ahi, const short* __restrict__ Alo,
    const short* __restrict__ Whi, const short* __restrict__ Wlo,
    const float* __restrict__ bias, const float* __restrict__ dis,
    float* __restrict__ Hs,
    int M, int K, int Nout, int MT, int MT8) {
    __shared__ __attribute__((aligned(16))) short lds[4][4096];

    // swizzled block decode: blk = xcd + 8*(n0t + 4*mt_local)
    int blk = blockIdx.x;
    int xcd = blk & 7;
    int r = blk >> 3;
    int n0t = r & 3;
    int mt = xcd * MT8 + (r >> 2);
    if (mt >= MT) return;                 // uniform across block; no barrier reached
    int m0 = mt * 128, n0 = n0t * 128;

    int tid = threadIdx.x;
    int w = tid >> 6, l = tid & 63;
    int lrow = l & 15, lq = l >> 4;

    const short* gp = (w == 0) ? Ahi : (w == 1) ? Alo : (w == 2) ? Whi : Wlo;
    int base_mn = (w < 2) ? m0 : n0;

    f32x4 acc[4][4];
    #pragma unroll
    for (int i = 0; i < 4; i++)
        #pragma unroll
        for (int j = 0; j < 4; j++) acc[i][j] = (f32x4){0.f, 0.f, 0.f, 0.f};

    int wm = w >> 1, wn = w & 1;

    for (int k0 = 0; k0 < K; k0 += 32) {
        const short* gbase = gp + (size_t)(base_mn + lrow) * K + (k0 + lq * 8);
        #pragma unroll
        for (int s = 0; s < 8; s++) {
            gload_lds16(gbase + (size_t)s * 16 * K, &lds[w][s * 64 * 8]);
        }
        __syncthreads();

        bf16x8 ah[4], al[4], wh[4], wl[4];
        #pragma unroll
        for (int i = 0; i < 4; i++) {
            int sA = wm * 4 + i;
            ah[i] = *(const bf16x8*)&lds[0][(sA * 64 + l) * 8];
            al[i] = *(const bf16x8*)&lds[1][(sA * 64 + l) * 8];
            int sW = wn * 4 + i;
            wh[i] = *(const bf16x8*)&lds[2][(sW * 64 + l) * 8];
            wl[i] = *(const bf16x8*)&lds[3][(sW * 64 + l) * 8];
        }
        #pragma unroll
        for (int i = 0; i < 4; i++)
            #pragma unroll
            for (int j = 0; j < 4; j++) {
                acc[i][j] = __builtin_amdgcn_mfma_f32_16x16x32_bf16(ah[i], wh[j], acc[i][j], 0, 0, 0);
                acc[i][j] = __builtin_amdgcn_mfma_f32_16x16x32_bf16(ah[i], wl[j], acc[i][j], 0, 0, 0);
                acc[i][j] = __builtin_amdgcn_mfma_f32_16x16x32_bf16(al[i], wh[j], acc[i][j], 0, 0, 0);
            }
        __syncthreads();
    }

    // hoisted per-row dis loads (16 independent, latency-hidden)
    float dv[4][4];
    #pragma unroll
    for (int i = 0; i < 4; i++) {
        int mrow = m0 + (wm * 4 + i) * 16 + lq * 4;
        #pragma unroll
        for (int rr = 0; rr < 4; rr++) {
            int mm = mrow + rr;
            dv[i][rr] = (mm < M) ? dis[mm] : 0.0f;
        }
    }

    // epilogue: C/D layout col=lane&15, row=(lane>>4)*4+reg
    #pragma unroll
    for (int j = 0; j < 4; j++) {
        int col = n0 + (wn * 4 + j) * 16 + lrow;
        float bv = bias[col];
        #pragma unroll
        for (int i = 0; i < 4; i++) {
            int mrow = m0 + (wm * 4 + i) * 16 + lq * 4;
            #pragma unroll
            for (int rr = 0; rr < 4; rr++) {
                int mm = mrow + rr;
                if (mm < M) Hs[(size_t)mm * Nout + col] = dv[i][rr] * (acc[i][j][rr] + bv);
            }
        }
    }
}

// ---------------- pooling: per-layer segment max + fraction positive ----------------
// grid (G, 8), 64 threads. Input is the dis-prescaled Hs; unscale with rdis[n].
__global__ __launch_bounds__(64) void pool_kernel(
    const float* __restrict__ Hs, const float* __restrict__ rdis,
    const int* __restrict__ starts,
    float* __restrict__ out, int layer) {
    int g = blockIdx.x;
    int c = blockIdx.y * 64 + threadIdx.x;   // 0..511
    int s = starts[g], e = starts[g + 1];
    float mx = -INFINITY;
    int pos = 0;
    #pragma unroll 4
    for (int n = s; n < e; n++) {
        float v = Hs[(size_t)n * HID + c] * rdis[n];
        mx = fmaxf(mx, v);
        pos += (v > 0.0f) ? 1 : 0;
    }
    float cntf = fmaxf((float)(e - s), 1.0f);
    out[(size_t)g * (8 * HID) + layer * HID + c] = mx;
    out[(size_t)g * (8 * HID) + 4 * HID + layer * HID + c] = (float)pos / cntf;
}

// ---------------- launcher ----------------
extern "C" void kernel_launch(void* const* d_in, const int* in_sizes, int n_in,
                              void* d_out, int out_size, void* d_ws, size_t ws_size,
                              hipStream_t stream) {
    const float* x     = (const float*)d_in[0];
    const int*   eidx  = (const int*)d_in[1];
    const int*   batch = (const int*)d_in[2];
    const float* W1 = (const float*)d_in[5];
    const float* b1 = (const float*)d_in[6];
    const float* W2 = (const float*)d_in[7];
    const float* b2 = (const float*)d_in[8];
    const float* W3 = (const float*)d_in[9];
    const float* b3 = (const float*)d_in[10];
    const float* W4 = (const float*)d_in[11];
    const float* b4 = (const float*)d_in[12];
    float* out = (float*)d_out;

    const int N = in_sizes[0] / F_IN;   // 20000
    const int E = in_sizes[1] / 2;      // 320000
    const int G = out_size / (8 * HID); // 256

    const int* src = eidx;
    const int* dst = eidx + E;

    // workspace layout (16B-aligned segments first)
    const size_t nW = (size_t)HID * F_IN + 3 * (size_t)HID * HID;
    char* w = (char*)d_ws;
    short* Ahi = (short*)w; w += (size_t)N * HID * sizeof(short);
    short* Alo = (short*)w; w += (size_t)N * HID * sizeof(short);
    float* Hs  = (float*)w; w += (size_t)N * HID * sizeof(float);
    float* xs  = (float*)w; w += (size_t)N * F_IN * sizeof(float);
    short* Whi = (short*)w; w += nW * sizeof(short);
    short* Wlo = (short*)w; w += nW * sizeof(short);
    int* offs  = (int*)w;   w += (size_t)(N + 4) * sizeof(int);
    unsigned short* csr = (unsigned short*)w; w += (size_t)E * sizeof(unsigned short);
    int* cnt   = (int*)w;   w += (size_t)N * sizeof(int);
    float* dis = (float*)w; w += (size_t)N * sizeof(float);
    float* rdis = (float*)w; w += (size_t)N * sizeof(float);
    int* starts = (int*)w;  w += (size_t)(G + 1) * sizeof(int);

    const size_t wo1 = 0;
    const size_t wo2 = (size_t)HID * F_IN;
    const size_t wo3 = wo2 + (size_t)HID * HID;
    const size_t wo4 = wo3 + (size_t)HID * HID;

    const int TB = 256;
    // ---- preprocessing: CSR over dst, dis, graph boundaries, W planes ----
    zero_kernel<<<(N + TB - 1) / TB, TB, 0, stream>>>(cnt, N);
    count_in_kernel<<<(E + TB - 1) / TB, TB, 0, stream>>>(dst, cnt, E);
    scan_kernel<<<1, 1024, 0, stream>>>(cnt, offs, N);
    dis_starts_kernel<<<(N + TB - 1) / TB, TB, 0, stream>>>(offs, dis, rdis, batch, starts, N, G);
    fill_csr_kernel<<<(E + TB - 1) / TB, TB, 0, stream>>>(src, dst, offs, cnt, csr, E);
    wconv_kernel<<<((int)nW + TB - 1) / TB, TB, 0, stream>>>(W1, W2, W3, W4, Whi, Wlo);
    xscale_kernel<<<(N * F_IN + TB - 1) / TB, TB, 0, stream>>>(x, dis, xs, N * F_IN);

    const int MT = (N + 127) / 128;        // 157 m-tiles
    const int MT8 = (MT + 7) / 8;          // per-XCD band
    const int gemm_blocks = 8 * MT8 * 4;   // 1D swizzled grid (some idle-guarded)
    dim3 pool_grid(G, HID / 64);

    const int NG = (N + 3) / 4;            // 4 nodes per 256-thread agg block
    const int agg1_blocks = NG * 4;        // CHUNKS=4,  PHASES=1, LOWB=4
    const int aggh_blocks = NG * 16;       // CHUNKS=16, PHASES=2, LOWB=8

    // ---- layer 1: h1 = (A x) @ W1^T + b1 ----
    agg_gather_kernel<F_IN, 4><<<agg1_blocks, 256, 0, stream>>>(xs, dis, offs, csr, Ahi, Alo, N);
    gemm_mfma_kernel<<<gemm_blocks, 256, 0, stream>>>(Ahi, Alo, Whi + wo1, Wlo + wo1, b1, dis, Hs,
                                                      N, F_IN, HID, MT, MT8);
    pool_kernel<<<pool_grid, 64, 0, stream>>>(Hs, rdis, starts, out, 0);

    // ---- layers 2..4 ----
    const size_t wos[3] = {wo2, wo3, wo4};
    const float* bs_[3] = {b2, b3, b4};
    for (int ll = 0; ll < 3; ll++) {
        agg_gather_kernel<HID, 16><<<aggh_blocks, 256, 0, stream>>>(Hs, dis, offs, csr, Ahi, Alo, N);
        gemm_mfma_kernel<<<gemm_blocks, 256, 0, stream>>>(Ahi, Alo, Whi + wos[ll], Wlo + wos[ll], bs_[ll], dis, Hs,
                                                          N, HID, HID, MT, MT8);
        pool_kernel<<<pool_grid, 64, 0, stream>>>(Hs, rdis, starts, out, ll + 1);
    }
}

// Round 7
// 694.715 us; speedup vs baseline: 1.1277x; 1.0895x over previous
//
#include <hip/hip_runtime.h>
#include <cfloat>
#include <cmath>

#define F_IN 128
#define HID 512

typedef short bf16x8 __attribute__((ext_vector_type(8)));
typedef float f32x4 __attribute__((ext_vector_type(4)));
typedef short s16x4 __attribute__((ext_vector_type(4)));

// ---- bf16 split helpers (RNE) ----
__device__ static inline void split_bf16(float v, short& hi, short& lo) {
    unsigned u = __float_as_uint(v);
    unsigned r = u + 0x7FFF + ((u >> 16) & 1);
    hi = (short)(r >> 16);
    float hf = __uint_as_float(((unsigned)(unsigned short)hi) << 16);
    float res = v - hf;
    unsigned u2 = __float_as_uint(res);
    unsigned r2 = u2 + 0x7FFF + ((u2 >> 16) & 1);
    lo = (short)(r2 >> 16);
}

__device__ static inline void gload_lds16(const void* g, void* l) {
    __builtin_amdgcn_global_load_lds(
        (const __attribute__((address_space(1))) unsigned int*)g,
        (__attribute__((address_space(3))) unsigned int*)l,
        16, 0, 0);
}

// ---------------- small utility kernels ----------------

__global__ void zero_kernel(int* __restrict__ a, int n) {
    int i = blockIdx.x * blockDim.x + threadIdx.x;
    if (i < n) a[i] = 0;
}

__global__ void count_in_kernel(const int* __restrict__ dst, int* __restrict__ cnt, int E) {
    int e = blockIdx.x * blockDim.x + threadIdx.x;
    if (e < E) atomicAdd(&cnt[dst[e]], 1);
}

// single-block scan (exclusive prefix sum); also writes offs[n] = total
__global__ void scan_kernel(const int* __restrict__ cnt, int* __restrict__ offs, int n) {
    __shared__ int buf[1024];
    __shared__ int carry_s;
    if (threadIdx.x == 0) carry_s = 0;
    __syncthreads();
    for (int base = 0; base < n; base += 1024) {
        int i = base + threadIdx.x;
        int v = (i < n) ? cnt[i] : 0;
        buf[threadIdx.x] = v;
        __syncthreads();
        for (int s = 1; s < 1024; s <<= 1) {
            int t = (threadIdx.x >= s) ? buf[threadIdx.x - s] : 0;
            __syncthreads();
            buf[threadIdx.x] += t;
            __syncthreads();
        }
        int total = buf[1023];
        if (i < n) offs[i] = carry_s + buf[threadIdx.x] - v;
        __syncthreads();
        if (threadIdx.x == 0) carry_s += total;
        __syncthreads();
    }
    if (threadIdx.x == 0) offs[n] = carry_s;
}

// dis (rsqrt) + rdis (sqrt, for pool unscale) + graph-boundary starts
__global__ void dis_starts_kernel(const int* __restrict__ offs, float* __restrict__ dis,
                                  float* __restrict__ rdis,
                                  const int* __restrict__ batch, int* __restrict__ starts,
                                  int n, int G) {
    int i = blockIdx.x * blockDim.x + threadIdx.x;
    if (i >= n) return;
    float degp1 = (float)(offs[i + 1] - offs[i] + 1);  // +1 self-loop
    dis[i] = rsqrtf(degp1);
    rdis[i] = sqrtf(degp1);
    int b = batch[i];
    if (i == 0) {
        for (int g = 0; g <= b; g++) starts[g] = 0;
    } else {
        int bp = batch[i - 1];
        for (int g = bp + 1; g <= b; g++) starts[g] = i;
    }
    if (i == n - 1) {
        for (int g = b + 1; g <= G; g++) starts[g] = n;
    }
}

// countdown-cursor fill: reuses cnt (holds deg) as cursor via atomicSub
__global__ void fill_csr_kernel(const int* __restrict__ src, const int* __restrict__ dst,
                                const int* __restrict__ offs, int* __restrict__ cnt,
                                unsigned short* __restrict__ csr, int E) {
    int e = blockIdx.x * blockDim.x + threadIdx.x;
    if (e < E) {
        int d = dst[e];
        int p = atomicSub(&cnt[d], 1);  // returns old value in [1, deg]
        csr[offs[d] + p - 1] = (unsigned short)src[e];
    }
}

// all-layer W fp32 -> bf16 hi/lo planes (single launch, concatenated)
__global__ void wconv_kernel(const float* __restrict__ W1, const float* __restrict__ W2,
                             const float* __restrict__ W3, const float* __restrict__ W4,
                             short* __restrict__ Whi, short* __restrict__ Wlo) {
    int i = blockIdx.x * blockDim.x + threadIdx.x;
    const int n1 = HID * F_IN, nk = HID * HID;
    float v;
    if (i < n1) v = W1[i];
    else if (i < n1 + nk) v = W2[i - n1];
    else if (i < n1 + 2 * nk) v = W3[i - n1 - nk];
    else if (i < n1 + 3 * nk) v = W4[i - n1 - 2 * nk];
    else return;
    short h, l;
    split_bf16(v, h, l);
    Whi[i] = h;
    Wlo[i] = l;
}

// layer-1 input prescale: xs[i][c] = dis[i] * x[i][c]  (F_IN = 128)
__global__ void xscale_kernel(const float* __restrict__ x, const float* __restrict__ dis,
                              float* __restrict__ xs, int total) {
    int i = blockIdx.x * blockDim.x + threadIdx.x;
    if (i < total) xs[i] = x[i] * dis[i >> 7];
}

// -------- float4-gather aggregation, 128-col waves, zero-row padding --------
// R6 post-mortem: agg was VALU-ISSUE-bound (VALUBusy 86%, FETCH 28 MB, HBM 9%):
// ~14 VALU ops per edge per 128 cols (scalar 4B gathers + cmp/cndmask
// predication + 320K-wave prologue overhead). This version:
//  - each lane gathers float4 (16B): 32 lanes = 128-col slice per edge,
//    2 edge-slots per wave -> 1 addr + 1 load per 32 elements (~5 VALU/edge/128c)
//  - predication REMOVED: invalid slots index the zeroed pad row Hs[n]
//    (written once; GEMM never touches row n) -> unconditional accumulate
//  - inner loop unrolled 4 batches = 8 edges -> 4 independent loads in flight
//  - CHUNKS 16->4 (HID): waves 320K->80K, 4x less fixed overhead.
// 128-col slice = 10 MB/XCD deliberately abandons strict L2 residency:
// R1-R6 proved memory is not the limiter (FETCH may rise; accepted).
template <int F, int CHUNKS>
__global__ __launch_bounds__(256) void agg_gather4_kernel(
    const float* __restrict__ Hs, const float* __restrict__ dis,
    const int* __restrict__ offs, const unsigned short* __restrict__ csr,
    short* __restrict__ Ahi, short* __restrict__ Alo, int n) {
    constexpr int CW = 128;                  // cols per wave (32 lanes x float4)
    int blk = blockIdx.x;
    int chunk = blk & (CHUNKS - 1);
    int gt = blk / CHUNKS;
    int wave = threadIdx.x >> 6;
    int i = gt * 4 + wave;                   // this wave's node
    if (i >= n) return;                      // wave-uniform; no barriers below

    int tid = threadIdx.x & 63;
    int es = tid >> 5;                       // edge slot 0/1
    int lq = tid & 31;                       // col-quad within slice
    int colbase = chunk * CW + lq * 4;
    const float* Hbase = Hs + colbase;

    int e0 = offs[i], e1 = offs[i + 1];
    float di = dis[i];

    f32x4 acc = (f32x4){0.f, 0.f, 0.f, 0.f};
    if (es == 0) acc = *(const f32x4*)(Hbase + (size_t)i * F);   // self term

    for (int w0 = e0; w0 < e1; w0 += 64) {
        int cnt = e1 - w0; if (cnt > 64) cnt = 64;
        int idx = n;                              // pad row (zeros)
        if (tid < cnt) idx = csr[w0 + tid];       // coalesced 2B x cnt
        int nb4 = (cnt + 7) >> 3;                 // groups of 4 batches (8 edges)
        for (int b = 0; b < nb4; b++) {
            int base = b * 8 + es;                // shfl src lane <= 63 always
            int j0 = __shfl(idx, base,     64);
            int j1 = __shfl(idx, base + 2, 64);
            int j2 = __shfl(idx, base + 4, 64);
            int j3 = __shfl(idx, base + 6, 64);
            f32x4 r0 = *(const f32x4*)(Hbase + (size_t)j0 * F);
            f32x4 r1 = *(const f32x4*)(Hbase + (size_t)j1 * F);
            f32x4 r2 = *(const f32x4*)(Hbase + (size_t)j2 * F);
            f32x4 r3 = *(const f32x4*)(Hbase + (size_t)j3 * F);
            acc[0] += (r0[0] + r1[0]) + (r2[0] + r3[0]);
            acc[1] += (r0[1] + r1[1]) + (r2[1] + r3[1]);
            acc[2] += (r0[2] + r1[2]) + (r2[2] + r3[2]);
            acc[3] += (r0[3] + r1[3]) + (r2[3] + r3[3]);
        }
    }
    // combine the two edge slots
    acc[0] += __shfl_xor(acc[0], 32, 64);
    acc[1] += __shfl_xor(acc[1], 32, 64);
    acc[2] += __shfl_xor(acc[2], 32, 64);
    acc[3] += __shfl_xor(acc[3], 32, 64);

    if (es == 0) {
        short h[4], l[4];
        #pragma unroll
        for (int q = 0; q < 4; q++) split_bf16(acc[q] * di, h[q], l[q]);
        *(s16x4*)&Ahi[(size_t)i * F + colbase] = (s16x4){h[0], h[1], h[2], h[3]};
        *(s16x4*)&Alo[(size_t)i * F + colbase] = (s16x4){l[0], l[1], l[2], l[3]};
    }
}

// -------- split-bf16 MFMA GEMM: Hs[M,N] = dis[m] * (A[M,K] @ W[N,K]^T + bias) --------
// A,W as bf16 hi/lo planes; 3 products hi*hi + hi*lo + lo*hi.
// Epilogue writes the dis-PRESCALED activation (consumed by next agg directly;
// pool unscales with rdis). Same write volume as before.
__global__ __launch_bounds__(256) void gemm_mfma_kernel(
    const short* __restrict__ Ahi, const short* __restrict__ Alo,
    const short* __restrict__ Whi, const short* __restrict__ Wlo,
    const float* __restrict__ bias, const float* __restrict__ dis,
    float* __restrict__ Hs,
    int M, int K, int Nout, int MT, int MT8) {
    __shared__ __attribute__((aligned(16))) short lds[4][4096];

    // swizzled block decode: blk = xcd + 8*(n0t + 4*mt_local)
    int blk = blockIdx.x;
    int xcd = blk & 7;
    int r = blk >> 3;
    int n0t = r & 3;
    int mt = xcd * MT8 + (r >> 2);
    if (mt >= MT) return;                 // uniform across block; no barrier reached
    int m0 = mt * 128, n0 = n0t * 128;

    int tid = threadIdx.x;
    int w = tid >> 6, l = tid & 63;
    int lrow = l & 15, lq = l >> 4;

    const short* gp = (w == 0) ? Ahi : (w == 1) ? Alo : (w == 2) ? Whi : Wlo;
    int base_mn = (w < 2) ? m0 : n0;

    f32x4 acc[4][4];
    #pragma unroll
    for (int i = 0; i < 4; i++)
        #pragma unroll
        for (int j = 0; j < 4; j++) acc[i][j] = (f32x4){0.f, 0.f, 0.f, 0.f};

    int wm = w >> 1, wn = w & 1;

    for (int k0 = 0; k0 < K; k0 += 32) {
        const short* gbase = gp + (size_t)(base_mn + lrow) * K + (k0 + lq * 8);
        #pragma unroll
        for (int s = 0; s < 8; s++) {
            gload_lds16(gbase + (size_t)s * 16 * K, &lds[w][s * 64 * 8]);
        }
        __syncthreads();

        bf16x8 ah[4], al[4], wh[4], wl[4];
        #pragma unroll
        for (int i = 0; i < 4; i++) {
            int sA = wm * 4 + i;
            ah[i] = *(const bf16x8*)&lds[0][(sA * 64 + l) * 8];
            al[i] = *(const bf16x8*)&lds[1][(sA * 64 + l) * 8];
            int sW = wn * 4 + i;
            wh[i] = *(const bf16x8*)&lds[2][(sW * 64 + l) * 8];
            wl[i] = *(const bf16x8*)&lds[3][(sW * 64 + l) * 8];
        }
        #pragma unroll
        for (int i = 0; i < 4; i++)
            #pragma unroll
            for (int j = 0; j < 4; j++) {
                acc[i][j] = __builtin_amdgcn_mfma_f32_16x16x32_bf16(ah[i], wh[j], acc[i][j], 0, 0, 0);
                acc[i][j] = __builtin_amdgcn_mfma_f32_16x16x32_bf16(ah[i], wl[j], acc[i][j], 0, 0, 0);
                acc[i][j] = __builtin_amdgcn_mfma_f32_16x16x32_bf16(al[i], wh[j], acc[i][j], 0, 0, 0);
            }
        __syncthreads();
    }

    // hoisted per-row dis loads (16 independent, latency-hidden)
    float dv[4][4];
    #pragma unroll
    for (int i = 0; i < 4; i++) {
        int mrow = m0 + (wm * 4 + i) * 16 + lq * 4;
        #pragma unroll
        for (int rr = 0; rr < 4; rr++) {
            int mm = mrow + rr;
            dv[i][rr] = (mm < M) ? dis[mm] : 0.0f;
        }
    }

    // epilogue: C/D layout col=lane&15, row=(lane>>4)*4+reg
    #pragma unroll
    for (int j = 0; j < 4; j++) {
        int col = n0 + (wn * 4 + j) * 16 + lrow;
        float bv = bias[col];
        #pragma unroll
        for (int i = 0; i < 4; i++) {
            int mrow = m0 + (wm * 4 + i) * 16 + lq * 4;
            #pragma unroll
            for (int rr = 0; rr < 4; rr++) {
                int mm = mrow + rr;
                if (mm < M) Hs[(size_t)mm * Nout + col] = dv[i][rr] * (acc[i][j][rr] + bv);
            }
        }
    }
}

// ---------------- pooling: per-layer segment max + fraction positive ----------------
// grid (G, 8), 64 threads. Input is the dis-prescaled Hs; unscale with rdis[n].
__global__ __launch_bounds__(64) void pool_kernel(
    const float* __restrict__ Hs, const float* __restrict__ rdis,
    const int* __restrict__ starts,
    float* __restrict__ out, int layer) {
    int g = blockIdx.x;
    int c = blockIdx.y * 64 + threadIdx.x;   // 0..511
    int s = starts[g], e = starts[g + 1];
    float mx = -INFINITY;
    int pos = 0;
    #pragma unroll 4
    for (int n = s; n < e; n++) {
        float v = Hs[(size_t)n * HID + c] * rdis[n];
        mx = fmaxf(mx, v);
        pos += (v > 0.0f) ? 1 : 0;
    }
    float cntf = fmaxf((float)(e - s), 1.0f);
    out[(size_t)g * (8 * HID) + layer * HID + c] = mx;
    out[(size_t)g * (8 * HID) + 4 * HID + layer * HID + c] = (float)pos / cntf;
}

// ---------------- launcher ----------------
extern "C" void kernel_launch(void* const* d_in, const int* in_sizes, int n_in,
                              void* d_out, int out_size, void* d_ws, size_t ws_size,
                              hipStream_t stream) {
    const float* x     = (const float*)d_in[0];
    const int*   eidx  = (const int*)d_in[1];
    const int*   batch = (const int*)d_in[2];
    const float* W1 = (const float*)d_in[5];
    const float* b1 = (const float*)d_in[6];
    const float* W2 = (const float*)d_in[7];
    const float* b2 = (const float*)d_in[8];
    const float* W3 = (const float*)d_in[9];
    const float* b3 = (const float*)d_in[10];
    const float* W4 = (const float*)d_in[11];
    const float* b4 = (const float*)d_in[12];
    float* out = (float*)d_out;

    const int N = in_sizes[0] / F_IN;   // 20000
    const int E = in_sizes[1] / 2;      // 320000
    const int G = out_size / (8 * HID); // 256

    const int* src = eidx;
    const int* dst = eidx + E;

    // workspace layout (16B-aligned segments first); Hs/xs have a zero pad row N
    const size_t nW = (size_t)HID * F_IN + 3 * (size_t)HID * HID;
    char* w = (char*)d_ws;
    short* Ahi = (short*)w; w += (size_t)N * HID * sizeof(short);
    short* Alo = (short*)w; w += (size_t)N * HID * sizeof(short);
    float* Hs  = (float*)w; w += (size_t)(N + 1) * HID * sizeof(float);
    float* xs  = (float*)w; w += (size_t)(N + 1) * F_IN * sizeof(float);
    short* Whi = (short*)w; w += nW * sizeof(short);
    short* Wlo = (short*)w; w += nW * sizeof(short);
    int* offs  = (int*)w;   w += (size_t)(N + 4) * sizeof(int);
    unsigned short* csr = (unsigned short*)w; w += (size_t)E * sizeof(unsigned short);
    int* cnt   = (int*)w;   w += (size_t)N * sizeof(int);
    float* dis = (float*)w; w += (size_t)N * sizeof(float);
    float* rdis = (float*)w; w += (size_t)N * sizeof(float);
    int* starts = (int*)w;  w += (size_t)(G + 1) * sizeof(int);

    const size_t wo1 = 0;
    const size_t wo2 = (size_t)HID * F_IN;
    const size_t wo3 = wo2 + (size_t)HID * HID;
    const size_t wo4 = wo3 + (size_t)HID * HID;

    const int TB = 256;
    // ---- preprocessing: CSR over dst, dis, graph boundaries, W planes ----
    zero_kernel<<<(N + TB - 1) / TB, TB, 0, stream>>>(cnt, N);
    zero_kernel<<<(HID + TB - 1) / TB, TB, 0, stream>>>((int*)(Hs + (size_t)N * HID), HID);
    zero_kernel<<<1, TB, 0, stream>>>((int*)(xs + (size_t)N * F_IN), F_IN);
    count_in_kernel<<<(E + TB - 1) / TB, TB, 0, stream>>>(dst, cnt, E);
    scan_kernel<<<1, 1024, 0, stream>>>(cnt, offs, N);
    dis_starts_kernel<<<(N + TB - 1) / TB, TB, 0, stream>>>(offs, dis, rdis, batch, starts, N, G);
    fill_csr_kernel<<<(E + TB - 1) / TB, TB, 0, stream>>>(src, dst, offs, cnt, csr, E);
    wconv_kernel<<<((int)nW + TB - 1) / TB, TB, 0, stream>>>(W1, W2, W3, W4, Whi, Wlo);
    xscale_kernel<<<(N * F_IN + TB - 1) / TB, TB, 0, stream>>>(x, dis, xs, N * F_IN);

    const int MT = (N + 127) / 128;        // 157 m-tiles
    const int MT8 = (MT + 7) / 8;          // per-XCD band
    const int gemm_blocks = 8 * MT8 * 4;   // 1D swizzled grid (some idle-guarded)
    dim3 pool_grid(G, HID / 64);

    const int NG = (N + 3) / 4;            // 4 nodes (waves) per 256-thread block
    const int agg1_blocks = NG * 1;        // F_IN=128: one 128-col chunk
    const int aggh_blocks = NG * 4;        // HID=512: four 128-col chunks

    // ---- layer 1: h1 = (A x) @ W1^T + b1 ----
    agg_gather4_kernel<F_IN, 1><<<agg1_blocks, 256, 0, stream>>>(xs, dis, offs, csr, Ahi, Alo, N);
    gemm_mfma_kernel<<<gemm_blocks, 256, 0, stream>>>(Ahi, Alo, Whi + wo1, Wlo + wo1, b1, dis, Hs,
                                                      N, F_IN, HID, MT, MT8);
    pool_kernel<<<pool_grid, 64, 0, stream>>>(Hs, rdis, starts, out, 0);

    // ---- layers 2..4 ----
    const size_t wos[3] = {wo2, wo3, wo4};
    const float* bs_[3] = {b2, b3, b4};
    for (int ll = 0; ll < 3; ll++) {
        agg_gather4_kernel<HID, 4><<<aggh_blocks, 256, 0, stream>>>(Hs, dis, offs, csr, Ahi, Alo, N);
        gemm_mfma_kernel<<<gemm_blocks, 256, 0, stream>>>(Ahi, Alo, Whi + wos[ll], Wlo + wos[ll], bs_[ll], dis, Hs,
                                                          N, HID, HID, MT, MT8);
        pool_kernel<<<pool_grid, 64, 0, stream>>>(Hs, rdis, starts, out, ll + 1);
    }
}